// Round 11
// baseline (237.877 us; speedup 1.0000x reference)
//
#include <hip/hip_runtime.h>
#include <hip/hip_fp16.h>
#include <float.h>

#define NN 10000
#define EE 320000
#define BB 4
#define DD 128
#define HH 4
#define DHH 32

union H4 { uint2 u2; __half2 h2[2]; };
union H8 { float4 f4; __half2 h2[4]; };

typedef _Float16 f16x8 __attribute__((ext_vector_type(8)));
typedef float f32x4 __attribute__((ext_vector_type(4)));

// Layouts: ALL batch-major (feat_h[(b*NN+n)*128], el/er[(b*NN+n)*4+h], hcat[(b*NN+n)*256]).
// The aggregate partitions batches across XCDs via blockIdx (round-robin %8 mapping),
// so each XCD's L2 holds one 2.56MB feat plane -> no capacity misses.

// ---------------- pack weights into per-lane MFMA B-fragments (fp16) + zero CSR counters
__global__ void pack_weights(const float* __restrict__ fc0, const float* __restrict__ fc1,
                             const float* __restrict__ mlp,
                             __half* __restrict__ bp0, __half* __restrict__ bp1,
                             __half* __restrict__ bpm,
                             int* __restrict__ cnt, int* __restrict__ cursor) {
    int s = blockIdx.x * 256 + threadIdx.x;  // 0..32767
    int i = s & 7, l = (s >> 3) & 63, ct = (s >> 9) & 7, kt = s >> 12;
    int k = kt * 32 + 8 * (l >> 4) + i;
    int o = ct * 16 + (l & 15);
    bpm[s] = __float2half(mlp[o * 256 + k]);
    if (s < 16384) {
        bp0[s] = __float2half(fc0[o * 128 + k]);
        bp1[s] = __float2half(fc1[o * 128 + k]);
    }
    if (s < NN) { cnt[s] = 0; cursor[s] = 0; }
}

// ---------------- CSR build ----------------
__global__ void count_edges(const int* __restrict__ dst, int* __restrict__ cnt) {
    int e = blockIdx.x * 256 + threadIdx.x;
    if (e < EE) atomicAdd(&cnt[dst[e]], 1);
}

__global__ void scan_kernel(const int* __restrict__ cnt, int* __restrict__ row_off) {
    __shared__ int part[1024];
    int t = threadIdx.x;
    const int CH = 10;  // 1024*10 >= NN
    int loc[CH];
    int s = 0;
#pragma unroll
    for (int j = 0; j < CH; ++j) {
        int i = t * CH + j;
        int v = (i < NN) ? cnt[i] : 0;
        loc[j] = s;
        s += v;
    }
    part[t] = s;
    __syncthreads();
    for (int off = 1; off < 1024; off <<= 1) {
        int v = (t >= off) ? part[t - off] : 0;
        __syncthreads();
        part[t] += v;
        __syncthreads();
    }
    int pre = (t > 0) ? part[t - 1] : 0;
#pragma unroll
    for (int j = 0; j < CH; ++j) {
        int i = t * CH + j;
        if (i < NN) row_off[i] = pre + loc[j];
    }
    if (t == 0) row_off[NN] = part[1023];
}

__global__ void scatter_edges(const int* __restrict__ dst, const int* __restrict__ row_off,
                              int* __restrict__ cursor, int* __restrict__ edge_ids) {
    int e = blockIdx.x * 256 + threadIdx.x;
    if (e < EE) {
        int d = dst[e];
        int p = atomicAdd(&cursor[d], 1);
        edge_ids[row_off[d] + p] = e;
    }
}

// ---------------- MFMA GEMM (verbatim R5/R6 — proven) ----------------
template <int K, bool A_HALF, bool HALF_OUT, bool BIAS>
__global__ __launch_bounds__(256) void mfma_gemm(
    const void* __restrict__ A_, int lda,
    const __half* __restrict__ Bp,
    const float* __restrict__ bias,
    __half* __restrict__ outh, float* __restrict__ outf, int ldo) {
    __shared__ __half A_s[64 * K];
    int tid = threadIdx.x;
    int row0 = blockIdx.x * 64;

    if (A_HALF) {
        const __half* A = (const __half*)A_;
#pragma unroll
        for (int it = 0; it < (64 * K / 8) / 256; ++it) {
            int s = it * 256 + tid;
            int r = s / (K / 8), c8 = s % (K / 8);
            uint4 v = *reinterpret_cast<const uint4*>(A + (size_t)(row0 + r) * lda + c8 * 8);
            int byte = (r * K + c8 * 8) * 2;
            byte ^= (r & 7) << 4;
            *reinterpret_cast<uint4*>((char*)A_s + byte) = v;
        }
    } else {
        const float* A = (const float*)A_;
#pragma unroll
        for (int it = 0; it < (64 * K / 4) / 256; ++it) {
            int s = it * 256 + tid;
            int r = s / (K / 4), c4 = s % (K / 4);
            float4 v = *reinterpret_cast<const float4*>(A + (size_t)(row0 + r) * lda + c4 * 4);
            __half h[4];
            h[0] = __float2half(v.x); h[1] = __float2half(v.y);
            h[2] = __float2half(v.z); h[3] = __float2half(v.w);
            int byte = (r * K + c4 * 4) * 2;
            byte ^= (r & 7) << 4;
            *reinterpret_cast<uint2*>((char*)A_s + byte) = *reinterpret_cast<uint2*>(h);
        }
    }
    __syncthreads();

    int l = tid & 63, w = tid >> 6;
    int g = l >> 4, r15 = l & 15;
    f32x4 acc[8] = {};

#pragma unroll
    for (int kt = 0; kt < K / 32; ++kt) {
        int row = w * 16 + r15;
        int byte = (row * K + kt * 32 + 8 * g) * 2;
        byte ^= (row & 7) << 4;
        f16x8 a = *reinterpret_cast<const f16x8*>((const char*)A_s + byte);
        const f16x8* bp = reinterpret_cast<const f16x8*>(Bp) + (size_t)(kt * 8) * 64 + l;
#pragma unroll
        for (int ct = 0; ct < 8; ++ct) {
            f16x8 b = bp[(size_t)ct * 64];
            acc[ct] = __builtin_amdgcn_mfma_f32_16x16x32_f16(a, b, acc[ct], 0, 0, 0);
        }
    }

#pragma unroll
    for (int ct = 0; ct < 8; ++ct) {
        int col = ct * 16 + r15;
#pragma unroll
        for (int reg = 0; reg < 4; ++reg) {
            int row = row0 + w * 16 + g * 4 + reg;
            float v = acc[ct][reg];
            if (BIAS) v += bias[col];
            if (HALF_OUT) outh[(size_t)row * ldo + col] = __float2half(v);
            else outf[(size_t)row * ldo + col] = v;
        }
    }
}

// ---------------- el/er from fp16 feat (verbatim R6) ----------------
__global__ __launch_bounds__(256) void elr_kernel(
    const __half* __restrict__ feat_h, const float* __restrict__ al,
    const float* __restrict__ ar, float* __restrict__ el, float* __restrict__ er) {
    __shared__ float s_al[128], s_ar[128];
    int tid = threadIdx.x;
    if (tid < 128) s_al[tid] = al[tid];
    else s_ar[tid - 128] = ar[tid - 128];
    __syncthreads();
    int idx = blockIdx.x * 256 + tid;  // (b*NN+n)*4 + h
    if (idx < BB * NN * HH) {
        int h = idx & 3;
        const __half* row = feat_h + (size_t)(idx >> 2) * 128 + h * 32;
        float al_acc = 0.f, ar_acc = 0.f;
#pragma unroll
        for (int q = 0; q < 8; ++q) {
            H4 u;
            u.u2 = *reinterpret_cast<const uint2*>(row + q * 4);
            float2 f0 = __half22float2(u.h2[0]);
            float2 f1 = __half22float2(u.h2[1]);
            int d = h * 32 + q * 4;
            al_acc += f0.x * s_al[d] + f0.y * s_al[d + 1] + f1.x * s_al[d + 2] + f1.y * s_al[d + 3];
            ar_acc += f0.x * s_ar[d] + f0.y * s_ar[d + 1] + f1.x * s_ar[d + 2] + f1.y * s_ar[d + 3];
        }
        el[idx] = al_acc;
        er[idx] = ar_acc;
    }
}

// ---------------- wave-per-(node,batch) fused aggregate, XCD-batch-partitioned ----------------
// Block g: batch b = (g&7)>>1 (round-robin g%8 -> XCD, so each XCD serves ONE 2.56MB
// feat plane, L2-resident); node group ngrp = (g>>3)*2 + (g&1); wave wv -> node ngrp*4+wv.
// Lane = (e4 = lane>>4, t = lane&15): 4 edges in flight; t covers bytes t*16 of the
// 256B feat row (h = t>>2, dims (t&3)*8). Score computed per lane for its h.
// den/acc summed over e4 groups by shfl_xor(16,32). Single-phase (no max subtraction:
// |sc| <= ~1.6). No barriers in main loop; LDS wave-private except read-only s_owt.
__global__ __launch_bounds__(256) void gat_aggregate(
    const int* __restrict__ row_off, const int* __restrict__ edge_ids,
    const int* __restrict__ src, const float* __restrict__ ew,
    const float* __restrict__ el, const float* __restrict__ er,
    const __half* __restrict__ feat_h, const float* __restrict__ out_w,
    const float* __restrict__ out_b, __half* __restrict__ hcat, int layer_off) {
    __shared__ float s_owt[32 * 33];     // out_w transposed [d][o]
    __shared__ int s_srcA[4][64];
    __shared__ float s_wA[4][64];
    __shared__ float s_aggA[4][132];     // per-wave agg: 4 heads x 32 dims (+pad)

    int tid = threadIdx.x;
    for (int i = tid; i < 1024; i += 256) {
        int o = i >> 5, d = i & 31;
        s_owt[d * 33 + o] = out_w[i];
    }
    __syncthreads();  // only block-wide barrier; s_owt read-only afterwards

    int g = blockIdx.x;
    int b = (g & 7) >> 1;
    int ngrp = ((g >> 3) << 1) | (g & 1);
    int wv = tid >> 6, lane = tid & 63;
    int n = ngrp * 4 + wv;
    int start = row_off[n], end = row_off[n + 1];

    int* s_src = s_srcA[wv];
    float* s_w = s_wA[wv];
    float* s_agg = s_aggA[wv];

    int e4 = lane >> 4, t = lane & 15;
    int h = t >> 2;
    const float* el_b = el + (size_t)b * NN * 4 + h;    // el[(b*NN+s)*4+h]
    float er1 = er[((size_t)b * NN + n) * 4 + h];
    const __half* fbase = feat_h + (size_t)b * NN * 128 + t * 8;

    float den = 0.f;
    float acc8[8];
#pragma unroll
    for (int i = 0; i < 8; ++i) acc8[i] = 0.f;

    for (int base = start; base < end; base += 64) {
        int cnum = end - base;
        if (cnum > 64) cnum = 64;
        // stage edge data (wave-private LDS; same-wave program order)
        if (lane < cnum) {
            int eid = edge_ids[base + lane];
            s_src[lane] = src[eid];
            s_w[lane] = ew[eid];
        }
        // fused loop: 4 edges in flight; per lane 16B of its edge's 256B row
#pragma unroll 4
        for (int j = e4; j < cnum; j += 4) {
            int s = s_src[j];
            float sc = el_b[(size_t)s * 4] + er1;
            sc = sc > 0.f ? sc : 0.1f * sc;
            sc *= s_w[j];
            float p = __expf(sc);
            den += p;
            H8 u;
            u.f4 = *reinterpret_cast<const float4*>(fbase + (size_t)s * 128);
            float2 f0 = __half22float2(u.h2[0]);
            float2 f1 = __half22float2(u.h2[1]);
            float2 f2 = __half22float2(u.h2[2]);
            float2 f3 = __half22float2(u.h2[3]);
            acc8[0] += p * f0.x; acc8[1] += p * f0.y;
            acc8[2] += p * f1.x; acc8[3] += p * f1.y;
            acc8[4] += p * f2.x; acc8[5] += p * f2.y;
            acc8[6] += p * f3.x; acc8[7] += p * f3.y;
        }
    }

    // reduce over e4 groups (lanes t, t+16, t+32, t+48)
    den += __shfl_xor(den, 16, 64);
    den += __shfl_xor(den, 32, 64);
#pragma unroll
    for (int i = 0; i < 8; ++i) {
        acc8[i] += __shfl_xor(acc8[i], 16, 64);
        acc8[i] += __shfl_xor(acc8[i], 32, 64);
    }
    float inv_den = (den == 0.f) ? 1.f : 1.f / den;
    if (e4 == 0) {
#pragma unroll
        for (int i = 0; i < 8; ++i) s_agg[t * 8 + i] = acc8[i] * inv_den;  // t*8 = h*32+(t&3)*8
    }

    // out_fc for this (n,b): lane = (h3 = lane>>4, sl = lane&3 -> 8 outputs), wave-private
    int h3 = lane >> 4, sl = lane & 3;
    float o_acc[8];
#pragma unroll
    for (int i = 0; i < 8; ++i) o_acc[i] = out_b[sl * 8 + i];
#pragma unroll 8
    for (int dd = 0; dd < 32; ++dd) {
        float a = s_agg[h3 * 32 + dd];
        const float* wr = s_owt + dd * 33 + sl * 8;
#pragma unroll
        for (int i = 0; i < 8; ++i) o_acc[i] += a * wr[i];
    }
    H8 ov;
#pragma unroll
    for (int k = 0; k < 4; ++k)
        ov.h2[k] = __floats2half2_rn(fmaxf(o_acc[2 * k], 0.f), fmaxf(o_acc[2 * k + 1], 0.f));
    *reinterpret_cast<float4*>(hcat + ((size_t)b * NN + n) * 256 + layer_off + h3 * 32 + sl * 8) = ov.f4;
}

extern "C" void kernel_launch(void* const* d_in, const int* in_sizes, int n_in,
                              void* d_out, int out_size, void* d_ws, size_t ws_size,
                              hipStream_t stream) {
    const float* features = (const float*)d_in[0];
    const int* src = (const int*)d_in[1];
    const int* dst = (const int*)d_in[2];
    const float* edge_w = (const float*)d_in[3];
    const float* fc_w0 = (const float*)d_in[4];
    const float* al0 = (const float*)d_in[5];
    const float* ar0 = (const float*)d_in[6];
    const float* out_w0 = (const float*)d_in[7];
    const float* out_b0 = (const float*)d_in[8];
    const float* fc_w1 = (const float*)d_in[9];
    const float* al1 = (const float*)d_in[10];
    const float* ar1 = (const float*)d_in[11];
    const float* out_w1 = (const float*)d_in[12];
    const float* out_b1 = (const float*)d_in[13];
    const float* mlp_w = (const float*)d_in[14];
    const float* mlp_b = (const float*)d_in[15];
    float* out = (float*)d_out;

    char* p = (char*)d_ws;
    auto take = [&](size_t bytes) {
        char* cur = p;
        p += (bytes + 255) & ~(size_t)255;
        return cur;
    };
    __half* bp0 = (__half*)take(16384 * 2);
    __half* bp1 = (__half*)take(16384 * 2);
    __half* bpm = (__half*)take(32768 * 2);
    __half* feat_h = (__half*)take((size_t)BB * NN * 128 * 2);
    __half* hcat = (__half*)take((size_t)BB * NN * 256 * 2);
    float* el = (float*)take((size_t)BB * NN * HH * 4);
    float* er = (float*)take((size_t)BB * NN * HH * 4);
    int* cnt = (int*)take((size_t)NN * 4);
    int* cursor = (int*)take((size_t)NN * 4);
    int* row_off = (int*)take((size_t)(NN + 1) * 4);
    int* edge_ids = (int*)take((size_t)EE * 4);
    (void)ws_size; (void)in_sizes; (void)n_in; (void)out_size;

    // weight prep (+ counter zeroing) + CSR build
    pack_weights<<<128, 256, 0, stream>>>(fc_w0, fc_w1, mlp_w, bp0, bp1, bpm, cnt, cursor);
    count_edges<<<EE / 256, 256, 0, stream>>>(dst, cnt);
    scan_kernel<<<1, 1024, 0, stream>>>(cnt, row_off);
    scatter_edges<<<EE / 256, 256, 0, stream>>>(dst, row_off, cursor, edge_ids);

    const int GEMM_GRID = (BB * NN) / 64;  // 625
    const int ELR_GRID = (BB * NN * HH + 255) / 256;  // 625
    const int AGG_GRID = NN;  // 2500 node-groups x 4 batches, XCD-partitioned

    // ---- layer 0 ----
    mfma_gemm<128, false, true, false><<<GEMM_GRID, 256, 0, stream>>>(
        features, 128, bp0, nullptr, feat_h, nullptr, 128);
    elr_kernel<<<ELR_GRID, 256, 0, stream>>>(feat_h, al0, ar0, el, er);
    gat_aggregate<<<AGG_GRID, 256, 0, stream>>>(row_off, edge_ids, src, edge_w, el, er,
                                                feat_h, out_w0, out_b0, hcat, 0);
    // ---- layer 1 ---- (input = hcat[:, 0:128] fp16, output -> hcat[:, 128:256])
    mfma_gemm<128, true, true, false><<<GEMM_GRID, 256, 0, stream>>>(
        hcat, 256, bp1, nullptr, feat_h, nullptr, 128);
    elr_kernel<<<ELR_GRID, 256, 0, stream>>>(feat_h, al1, ar1, el, er);
    gat_aggregate<<<AGG_GRID, 256, 0, stream>>>(row_off, edge_ids, src, edge_w, el, er,
                                                feat_h, out_w1, out_b1, hcat, 128);
    // ---- MLP head ---- (A = hcat fp16, K=256, fp32 out + bias)
    mfma_gemm<256, true, false, true><<<GEMM_GRID, 256, 0, stream>>>(
        hcat, 256, bpm, mlp_b, nullptr, out, 128);
}

// Round 12
// 237.760 us; speedup vs baseline: 1.0005x; 1.0005x over previous
//
#include <hip/hip_runtime.h>
#include <hip/hip_fp16.h>
#include <float.h>

#define NN 10000
#define EE 320000
#define BB 4
#define DD 128
#define HH 4
#define DHH 32
#define NPASS 4
#define WIN 2500   // NN/NPASS: 2500 nodes * 1KB feat = 2.56MB < 4MB per-XCD L2

union H4 { uint2 u2; __half2 h2[2]; };
union H8 { float4 f4; __half2 h2[4]; };

typedef _Float16 f16x8 __attribute__((ext_vector_type(8)));
typedef float f32x4 __attribute__((ext_vector_type(4)));

// All intermediate tensors are NODE-MAJOR: row r = n*4 + b.
//   feat_h[r][128]  (one edge's 4-batch payload = contiguous 1KB)
//   el/er[n*16 + b*4 + h]
//   hcat[r][256]
// features (input) and out (output) stay batch-major; GEMM C-writes remap.

// ---------------- pack weights into per-lane MFMA B-fragments (fp16) + zero CSR counters
__global__ void pack_weights(const float* __restrict__ fc0, const float* __restrict__ fc1,
                             const float* __restrict__ mlp,
                             __half* __restrict__ bp0, __half* __restrict__ bp1,
                             __half* __restrict__ bpm,
                             int* __restrict__ cnt, int* __restrict__ cursor) {
    int s = blockIdx.x * 256 + threadIdx.x;  // 0..32767
    int i = s & 7, l = (s >> 3) & 63, ct = (s >> 9) & 7, kt = s >> 12;
    int k = kt * 32 + 8 * (l >> 4) + i;
    int o = ct * 16 + (l & 15);
    bpm[s] = __float2half(mlp[o * 256 + k]);
    if (s < 16384) {
        bp0[s] = __float2half(fc0[o * 128 + k]);
        bp1[s] = __float2half(fc1[o * 128 + k]);
    }
    if (s < NN) { cnt[s] = 0; cursor[s] = 0; }
}

// ---------------- CSR build ----------------
__global__ void count_edges(const int* __restrict__ dst, int* __restrict__ cnt) {
    int e = blockIdx.x * 256 + threadIdx.x;
    if (e < EE) atomicAdd(&cnt[dst[e]], 1);
}

__global__ void scan_kernel(const int* __restrict__ cnt, int* __restrict__ row_off) {
    __shared__ int part[1024];
    int t = threadIdx.x;
    const int CH = 10;  // 1024*10 >= NN
    int loc[CH];
    int s = 0;
#pragma unroll
    for (int j = 0; j < CH; ++j) {
        int i = t * CH + j;
        int v = (i < NN) ? cnt[i] : 0;
        loc[j] = s;
        s += v;
    }
    part[t] = s;
    __syncthreads();
    for (int off = 1; off < 1024; off <<= 1) {
        int v = (t >= off) ? part[t - off] : 0;
        __syncthreads();
        part[t] += v;
        __syncthreads();
    }
    int pre = (t > 0) ? part[t - 1] : 0;
#pragma unroll
    for (int j = 0; j < CH; ++j) {
        int i = t * CH + j;
        if (i < NN) row_off[i] = pre + loc[j];
    }
    if (t == 0) row_off[NN] = part[1023];
}

__global__ void scatter_edges(const int* __restrict__ dst, const int* __restrict__ row_off,
                              int* __restrict__ cursor, int* __restrict__ edge_ids) {
    int e = blockIdx.x * 256 + threadIdx.x;
    if (e < EE) {
        int d = dst[e];
        int p = atomicAdd(&cursor[d], 1);
        edge_ids[row_off[d] + p] = e;
    }
}

// ---------------- MFMA GEMM (R5-proven core; REMAP on C-row only) ----------------
// REMAP: 0 = identity, 1 = batch-major A-row -> node-major out, 2 = node-major -> batch-major
template <int K, int REMAP, bool A_HALF, bool HALF_OUT, bool BIAS>
__global__ __launch_bounds__(256) void mfma_gemm(
    const void* __restrict__ A_, int lda,
    const __half* __restrict__ Bp,
    const float* __restrict__ bias,
    __half* __restrict__ outh, float* __restrict__ outf, int ldo) {
    __shared__ __half A_s[64 * K];
    int tid = threadIdx.x;
    int row0 = blockIdx.x * 64;

    if (A_HALF) {
        const __half* A = (const __half*)A_;
#pragma unroll
        for (int it = 0; it < (64 * K / 8) / 256; ++it) {
            int s = it * 256 + tid;
            int r = s / (K / 8), c8 = s % (K / 8);
            uint4 v = *reinterpret_cast<const uint4*>(A + (size_t)(row0 + r) * lda + c8 * 8);
            int byte = (r * K + c8 * 8) * 2;
            byte ^= (r & 7) << 4;
            *reinterpret_cast<uint4*>((char*)A_s + byte) = v;
        }
    } else {
        const float* A = (const float*)A_;
#pragma unroll
        for (int it = 0; it < (64 * K / 4) / 256; ++it) {
            int s = it * 256 + tid;
            int r = s / (K / 4), c4 = s % (K / 4);
            float4 v = *reinterpret_cast<const float4*>(A + (size_t)(row0 + r) * lda + c4 * 4);
            __half h[4];
            h[0] = __float2half(v.x); h[1] = __float2half(v.y);
            h[2] = __float2half(v.z); h[3] = __float2half(v.w);
            int byte = (r * K + c4 * 4) * 2;
            byte ^= (r & 7) << 4;
            *reinterpret_cast<uint2*>((char*)A_s + byte) = *reinterpret_cast<uint2*>(h);
        }
    }
    __syncthreads();

    int l = tid & 63, w = tid >> 6;
    int g = l >> 4, r15 = l & 15;
    f32x4 acc[8] = {};

#pragma unroll
    for (int kt = 0; kt < K / 32; ++kt) {
        int row = w * 16 + r15;
        int byte = (row * K + kt * 32 + 8 * g) * 2;
        byte ^= (row & 7) << 4;
        f16x8 a = *reinterpret_cast<const f16x8*>((const char*)A_s + byte);
        const f16x8* bp = reinterpret_cast<const f16x8*>(Bp) + (size_t)(kt * 8) * 64 + l;
#pragma unroll
        for (int ct = 0; ct < 8; ++ct) {
            f16x8 b = bp[(size_t)ct * 64];
            acc[ct] = __builtin_amdgcn_mfma_f32_16x16x32_f16(a, b, acc[ct], 0, 0, 0);
        }
    }

    int grow[4];
#pragma unroll
    for (int reg = 0; reg < 4; ++reg) {
        int r = row0 + w * 16 + g * 4 + reg;
        if (REMAP == 0) grow[reg] = r;
        else if (REMAP == 1) { int n = r % NN, b = r / NN; grow[reg] = n * 4 + b; }
        else grow[reg] = (r & 3) * NN + (r >> 2);
    }
#pragma unroll
    for (int ct = 0; ct < 8; ++ct) {
        int col = ct * 16 + r15;
#pragma unroll
        for (int reg = 0; reg < 4; ++reg) {
            float v = acc[ct][reg];
            if (BIAS) v += bias[col];
            if (HALF_OUT) outh[(size_t)grow[reg] * ldo + col] = __float2half(v);
            else outf[(size_t)grow[reg] * ldo + col] = v;
        }
    }
}

// ---------------- el/er from fp16 feat (node-major rows) ----------------
__global__ __launch_bounds__(256) void elr_kernel(
    const __half* __restrict__ feat_h, const float* __restrict__ al,
    const float* __restrict__ ar, float* __restrict__ el, float* __restrict__ er) {
    __shared__ float s_al[128], s_ar[128];
    int tid = threadIdx.x;
    if (tid < 128) s_al[tid] = al[tid];
    else s_ar[tid - 128] = ar[tid - 128];
    __syncthreads();
    int idx = blockIdx.x * 256 + tid;  // r*4 + h, r node-major
    if (idx < BB * NN * HH) {
        int h = idx & 3;
        const __half* row = feat_h + (size_t)(idx >> 2) * 128 + h * 32;
        float al_acc = 0.f, ar_acc = 0.f;
#pragma unroll
        for (int q = 0; q < 8; ++q) {
            H4 u;
            u.u2 = *reinterpret_cast<const uint2*>(row + q * 4);
            float2 f0 = __half22float2(u.h2[0]);
            float2 f1 = __half22float2(u.h2[1]);
            int d = h * 32 + q * 4;
            al_acc += f0.x * s_al[d] + f0.y * s_al[d + 1] + f1.x * s_al[d + 2] + f1.y * s_al[d + 3];
            ar_acc += f0.x * s_ar[d] + f0.y * s_ar[d + 1] + f1.x * s_ar[d + 2] + f1.y * s_ar[d + 3];
        }
        el[idx] = al_acc;
        er[idx] = ar_acc;
    }
}

// ---------------- wave-per-node aggregate, single-phase, coalesced, SRC-WINDOWED ----------------
// R10-proven skeleton. New: NPASS passes over the edge list; pass p gathers only edges
// with src in [p*WIN, p*WIN+WIN) — a 2.56MB feat window that stays L2-resident while
// the (nearly fully co-resident) grid sweeps windows in rough lockstep. The window
// test is WAVE-UNIFORM (whole wave handles one edge), so skipped edges cost ~4 ops.
// den/acc are linear sums -> accumulate across passes with no extra math.
__global__ __launch_bounds__(256) void gat_aggregate(
    const int* __restrict__ row_off, const int* __restrict__ edge_ids,
    const int* __restrict__ src, const float* __restrict__ ew,
    const float* __restrict__ el, const float* __restrict__ er,
    const __half* __restrict__ feat_h, const float* __restrict__ out_w,
    const float* __restrict__ out_b, __half* __restrict__ hcat, int layer_off) {
    __shared__ float s_owt[32 * 33];      // out_w transposed [d][o]
    __shared__ int s_srcA[4][64];
    __shared__ float s_wA[4][64];
    __shared__ float s_aggA[4][16 * 33];  // epilogue staging

    int tid = threadIdx.x;
    for (int i = tid; i < 1024; i += 256) {
        int o = i >> 5, d = i & 31;
        s_owt[d * 33 + o] = out_w[i];
    }
    __syncthreads();  // only block-wide barrier; s_owt read-only afterwards

    int wv = tid >> 6, lane = tid & 63;
    int n = blockIdx.x * 4 + wv;
    int start = row_off[n], end = row_off[n + 1];
    int* s_src = s_srcA[wv];
    float* s_w = s_wA[wv];
    float* s_agg = s_aggA[wv];

    int bh4 = lane >> 2, sl = lane & 3;
    float er1 = er[(size_t)n * 16 + bh4];
    const float* el_base = el + bh4;             // el[s*16 + bh4]
    const __half* fbase = feat_h + lane * 8;     // feat[s*512 + lane*8]

    float den = 0.f;
    float acc8[8];
#pragma unroll
    for (int i = 0; i < 8; ++i) acc8[i] = 0.f;

    for (int pass = 0; pass < NPASS; ++pass) {
        int lo = pass * WIN, hi = lo + WIN;
        for (int base = start; base < end; base += 64) {
            int cnum = end - base;
            if (cnum > 64) cnum = 64;
            // stage edge data (wave-private LDS; same-wave program order; cheap re-stage)
            if (lane < cnum) {
                int eid = edge_ids[base + lane];
                s_src[lane] = src[eid];
                s_w[lane] = ew[eid];
            }
#pragma unroll 4
            for (int j = 0; j < cnum; ++j) {
                int s = s_src[j];
                if (s >= lo && s < hi) {   // wave-uniform branch
                    float sc = el_base[(size_t)s * 16] + er1;
                    sc = sc > 0.f ? sc : 0.1f * sc;
                    sc *= s_w[j];
                    float p = __expf(sc);
                    den += p;
                    H8 u;
                    u.f4 = *reinterpret_cast<const float4*>(fbase + (size_t)s * 512);
                    float2 f0 = __half22float2(u.h2[0]);
                    float2 f1 = __half22float2(u.h2[1]);
                    float2 f2 = __half22float2(u.h2[2]);
                    float2 f3 = __half22float2(u.h2[3]);
                    acc8[0] += p * f0.x; acc8[1] += p * f0.y;
                    acc8[2] += p * f1.x; acc8[3] += p * f1.y;
                    acc8[4] += p * f2.x; acc8[5] += p * f2.y;
                    acc8[6] += p * f3.x; acc8[7] += p * f3.y;
                }
            }
        }
    }

    // epilogue: normalize -> s_agg (wave-private), out_fc + relu -> hcat fp16
    float inv_den = (den == 0.f) ? 1.f : 1.f / den;
#pragma unroll
    for (int i = 0; i < 8; ++i) s_agg[bh4 * 33 + sl * 8 + i] = acc8[i] * inv_den;

    float o_acc[8];
#pragma unroll
    for (int i = 0; i < 8; ++i) o_acc[i] = out_b[sl * 8 + i];
#pragma unroll 8
    for (int dd = 0; dd < 32; ++dd) {
        float a = s_agg[bh4 * 33 + dd];
        const float* wr = s_owt + dd * 33 + sl * 8;
#pragma unroll
        for (int i = 0; i < 8; ++i) o_acc[i] += a * wr[i];
    }
    H8 ov;
#pragma unroll
    for (int k = 0; k < 4; ++k)
        ov.h2[k] = __floats2half2_rn(fmaxf(o_acc[2 * k], 0.f), fmaxf(o_acc[2 * k + 1], 0.f));
    // hcat row = n*4 + b, offset layer_off + h*32 + sl*8   (b = bh4>>2, h = bh4&3)
    int b = bh4 >> 2, h = bh4 & 3;
    *reinterpret_cast<float4*>(hcat + ((size_t)(n * 4 + b)) * 256 + layer_off + h * 32 + sl * 8) = ov.f4;
}

extern "C" void kernel_launch(void* const* d_in, const int* in_sizes, int n_in,
                              void* d_out, int out_size, void* d_ws, size_t ws_size,
                              hipStream_t stream) {
    const float* features = (const float*)d_in[0];
    const int* src = (const int*)d_in[1];
    const int* dst = (const int*)d_in[2];
    const float* edge_w = (const float*)d_in[3];
    const float* fc_w0 = (const float*)d_in[4];
    const float* al0 = (const float*)d_in[5];
    const float* ar0 = (const float*)d_in[6];
    const float* out_w0 = (const float*)d_in[7];
    const float* out_b0 = (const float*)d_in[8];
    const float* fc_w1 = (const float*)d_in[9];
    const float* al1 = (const float*)d_in[10];
    const float* ar1 = (const float*)d_in[11];
    const float* out_w1 = (const float*)d_in[12];
    const float* out_b1 = (const float*)d_in[13];
    const float* mlp_w = (const float*)d_in[14];
    const float* mlp_b = (const float*)d_in[15];
    float* out = (float*)d_out;

    char* p = (char*)d_ws;
    auto take = [&](size_t bytes) {
        char* cur = p;
        p += (bytes + 255) & ~(size_t)255;
        return cur;
    };
    __half* bp0 = (__half*)take(16384 * 2);
    __half* bp1 = (__half*)take(16384 * 2);
    __half* bpm = (__half*)take(32768 * 2);
    __half* feat_h = (__half*)take((size_t)BB * NN * 128 * 2);
    __half* hcat = (__half*)take((size_t)BB * NN * 256 * 2);
    float* el = (float*)take((size_t)BB * NN * HH * 4);
    float* er = (float*)take((size_t)BB * NN * HH * 4);
    int* cnt = (int*)take((size_t)NN * 4);
    int* cursor = (int*)take((size_t)NN * 4);
    int* row_off = (int*)take((size_t)(NN + 1) * 4);
    int* edge_ids = (int*)take((size_t)EE * 4);
    (void)ws_size; (void)in_sizes; (void)n_in; (void)out_size;

    // weight prep (+ counter zeroing) + CSR build
    pack_weights<<<128, 256, 0, stream>>>(fc_w0, fc_w1, mlp_w, bp0, bp1, bpm, cnt, cursor);
    count_edges<<<EE / 256, 256, 0, stream>>>(dst, cnt);
    scan_kernel<<<1, 1024, 0, stream>>>(cnt, row_off);
    scatter_edges<<<EE / 256, 256, 0, stream>>>(dst, row_off, cursor, edge_ids);

    const int GEMM_GRID = (BB * NN) / 64;  // 625
    const int ELR_GRID = (BB * NN * HH + 255) / 256;  // 625
    const int AGG_GRID = NN / 4;  // 2500

    // ---- layer 0 ---- (A batch-major features -> node-major feat)
    mfma_gemm<128, 1, false, true, false><<<GEMM_GRID, 256, 0, stream>>>(
        features, 128, bp0, nullptr, feat_h, nullptr, 128);
    elr_kernel<<<ELR_GRID, 256, 0, stream>>>(feat_h, al0, ar0, el, er);
    gat_aggregate<<<AGG_GRID, 256, 0, stream>>>(row_off, edge_ids, src, edge_w, el, er,
                                                feat_h, out_w0, out_b0, hcat, 0);
    // ---- layer 1 ---- (A = hcat[:,0:128] node-major -> node-major feat; identity remap)
    mfma_gemm<128, 0, true, true, false><<<GEMM_GRID, 256, 0, stream>>>(
        hcat, 256, bp1, nullptr, feat_h, nullptr, 128);
    elr_kernel<<<ELR_GRID, 256, 0, stream>>>(feat_h, al1, ar1, el, er);
    gat_aggregate<<<AGG_GRID, 256, 0, stream>>>(row_off, edge_ids, src, edge_w, el, er,
                                                feat_h, out_w1, out_b1, hcat, 128);
    // ---- MLP head ---- (A = hcat node-major, K=256; C-write back to batch-major out)
    mfma_gemm<256, 2, true, false, true><<<GEMM_GRID, 256, 0, stream>>>(
        hcat, 256, bpm, mlp_b, nullptr, out, 128);
}

// Round 13
// 203.643 us; speedup vs baseline: 1.1681x; 1.1675x over previous
//
#include <hip/hip_runtime.h>
#include <hip/hip_fp16.h>
#include <float.h>

#define NN 10000
#define EE 320000
#define BB 4
#define DD 128
#define HH 4
#define DHH 32

union H4 { uint2 u2; __half2 h2[2]; };
union H8 { float4 f4; __half2 h2[4]; };

typedef _Float16 f16x8 __attribute__((ext_vector_type(8)));
typedef float f32x4 __attribute__((ext_vector_type(4)));

// All intermediate tensors are NODE-MAJOR: row r = n*4 + b.
//   feat_h[r][128]  (one edge's 4-batch payload = contiguous 1KB)
//   el/er[r*4 + h] = [n*16 + b*4 + h]
//   hcat[r][256]
// features (input) and out (output) stay batch-major; GEMM C-writes remap.

// ---------------- pack weights into per-lane MFMA B-fragments (fp16) + zero CSR counters
__global__ void pack_weights(const float* __restrict__ fc0, const float* __restrict__ fc1,
                             const float* __restrict__ mlp,
                             __half* __restrict__ bp0, __half* __restrict__ bp1,
                             __half* __restrict__ bpm,
                             int* __restrict__ cnt, int* __restrict__ cursor) {
    int s = blockIdx.x * 256 + threadIdx.x;  // 0..32767
    int i = s & 7, l = (s >> 3) & 63, ct = (s >> 9) & 7, kt = s >> 12;
    int k = kt * 32 + 8 * (l >> 4) + i;
    int o = ct * 16 + (l & 15);
    bpm[s] = __float2half(mlp[o * 256 + k]);
    if (s < 16384) {
        bp0[s] = __float2half(fc0[o * 128 + k]);
        bp1[s] = __float2half(fc1[o * 128 + k]);
    }
    if (s < NN) { cnt[s] = 0; cursor[s] = 0; }
}

// ---------------- CSR build ----------------
__global__ void count_edges(const int* __restrict__ dst, int* __restrict__ cnt) {
    int e = blockIdx.x * 256 + threadIdx.x;
    if (e < EE) atomicAdd(&cnt[dst[e]], 1);
}

// 1024 threads, CH=10: wave-shuffle prefix, only 2 barriers.
__global__ void scan_kernel(const int* __restrict__ cnt, int* __restrict__ row_off) {
    __shared__ int part[16];
    int t = threadIdx.x;
    int lane = t & 63, wv = t >> 6;
    const int CH = 10;
    int loc[CH];
    int s = 0;
#pragma unroll
    for (int j = 0; j < CH; ++j) {
        int i = t * CH + j;
        int v = (i < NN) ? cnt[i] : 0;
        loc[j] = s;
        s += v;
    }
    // inclusive scan of s over the 64 lanes
    int x = s;
#pragma unroll
    for (int off = 1; off < 64; off <<= 1) {
        int y = __shfl_up(x, off, 64);
        if (lane >= off) x += y;
    }
    if (lane == 63) part[wv] = x;
    __syncthreads();
    if (t == 0) {
        int a = 0;
#pragma unroll
        for (int w = 0; w < 16; ++w) { int v = part[w]; part[w] = a; a += v; }
    }
    __syncthreads();
    int base = part[wv] + (x - s);  // exclusive prefix for this thread
#pragma unroll
    for (int j = 0; j < CH; ++j) {
        int i = t * CH + j;
        if (i < NN) row_off[i] = base + loc[j];
    }
    if (t == 1023) row_off[NN] = base + s;
}

__global__ void scatter_edges(const int* __restrict__ dst, const int* __restrict__ row_off,
                              int* __restrict__ cursor, int* __restrict__ edge_ids) {
    int e = blockIdx.x * 256 + threadIdx.x;
    if (e < EE) {
        int d = dst[e];
        int p = atomicAdd(&cursor[d], 1);
        edge_ids[row_off[d] + p] = e;
    }
}

// ---------------- MFMA GEMM (R5-proven core; REMAP on C-row; optional fused el/er) ----------------
// REMAP: 0 = identity, 1 = batch-major A-row -> node-major out, 2 = node-major -> batch-major
// ATTN: el/er computed from fp32 accumulators; cross-lane reduce over r15 (masks 1,2,4,8).
template <int K, int REMAP, bool A_HALF, bool ATTN, bool HALF_OUT, bool BIAS>
__global__ __launch_bounds__(256) void mfma_gemm(
    const void* __restrict__ A_, int lda,
    const __half* __restrict__ Bp,
    const float* __restrict__ al, const float* __restrict__ ar,
    const float* __restrict__ bias,
    __half* __restrict__ outh, float* __restrict__ outf, int ldo,
    float* __restrict__ el_out, float* __restrict__ er_out) {
    __shared__ __half A_s[64 * K];
    int tid = threadIdx.x;
    int row0 = blockIdx.x * 64;

    if (A_HALF) {
        const __half* A = (const __half*)A_;
#pragma unroll
        for (int it = 0; it < (64 * K / 8) / 256; ++it) {
            int s = it * 256 + tid;
            int r = s / (K / 8), c8 = s % (K / 8);
            uint4 v = *reinterpret_cast<const uint4*>(A + (size_t)(row0 + r) * lda + c8 * 8);
            int byte = (r * K + c8 * 8) * 2;
            byte ^= (r & 7) << 4;
            *reinterpret_cast<uint4*>((char*)A_s + byte) = v;
        }
    } else {
        const float* A = (const float*)A_;
#pragma unroll
        for (int it = 0; it < (64 * K / 4) / 256; ++it) {
            int s = it * 256 + tid;
            int r = s / (K / 4), c4 = s % (K / 4);
            float4 v = *reinterpret_cast<const float4*>(A + (size_t)(row0 + r) * lda + c4 * 4);
            __half h[4];
            h[0] = __float2half(v.x); h[1] = __float2half(v.y);
            h[2] = __float2half(v.z); h[3] = __float2half(v.w);
            int byte = (r * K + c4 * 4) * 2;
            byte ^= (r & 7) << 4;
            *reinterpret_cast<uint2*>((char*)A_s + byte) = *reinterpret_cast<uint2*>(h);
        }
    }
    __syncthreads();

    int l = tid & 63, w = tid >> 6;
    int g = l >> 4, r15 = l & 15;
    f32x4 acc[8] = {};

#pragma unroll
    for (int kt = 0; kt < K / 32; ++kt) {
        int row = w * 16 + r15;
        int byte = (row * K + kt * 32 + 8 * g) * 2;
        byte ^= (row & 7) << 4;
        f16x8 a = *reinterpret_cast<const f16x8*>((const char*)A_s + byte);
        const f16x8* bp = reinterpret_cast<const f16x8*>(Bp) + (size_t)(kt * 8) * 64 + l;
#pragma unroll
        for (int ct = 0; ct < 8; ++ct) {
            f16x8 b = bp[(size_t)ct * 64];
            acc[ct] = __builtin_amdgcn_mfma_f32_16x16x32_f16(a, b, acc[ct], 0, 0, 0);
        }
    }

    int grow[4];
#pragma unroll
    for (int reg = 0; reg < 4; ++reg) {
        int r = row0 + w * 16 + g * 4 + reg;
        if (REMAP == 0) grow[reg] = r;
        else if (REMAP == 1) { int n = r % NN, b = r / NN; grow[reg] = n * 4 + b; }
        else grow[reg] = (r & 3) * NN + (r >> 2);
    }
#pragma unroll
    for (int ct = 0; ct < 8; ++ct) {
        int col = ct * 16 + r15;
#pragma unroll
        for (int reg = 0; reg < 4; ++reg) {
            float v = acc[ct][reg];
            if (BIAS) v += bias[col];
            if (HALF_OUT) outh[(size_t)grow[reg] * ldo + col] = __float2half(v);
            else outf[(size_t)grow[reg] * ldo + col] = v;
        }
    }

    if (ATTN) {
        // el[row][h] = sum over head cols (ct = 2h, 2h+1, 16 r15-lanes) of acc*al
#pragma unroll
        for (int h = 0; h < 4; ++h) {
            float a0 = al[(2 * h) * 16 + r15], a1 = al[(2 * h + 1) * 16 + r15];
            float b0 = ar[(2 * h) * 16 + r15], b1 = ar[(2 * h + 1) * 16 + r15];
            f32x4 pe, pr;
#pragma unroll
            for (int reg = 0; reg < 4; ++reg) {
                pe[reg] = acc[2 * h][reg] * a0 + acc[2 * h + 1][reg] * a1;
                pr[reg] = acc[2 * h][reg] * b0 + acc[2 * h + 1][reg] * b1;
            }
#pragma unroll
            for (int mk = 1; mk <= 8; mk <<= 1) {
#pragma unroll
                for (int reg = 0; reg < 4; ++reg) {
                    pe[reg] += __shfl_xor(pe[reg], mk, 64);
                    pr[reg] += __shfl_xor(pr[reg], mk, 64);
                }
            }
            if (r15 == 0) {
#pragma unroll
                for (int reg = 0; reg < 4; ++reg) {
                    el_out[grow[reg] * 4 + h] = pe[reg];
                    er_out[grow[reg] * 4 + h] = pr[reg];
                }
            }
        }
    }
}

// ---------------- wave-per-node aggregate (verbatim R10 — proven 53 us, replay-safe) ----------------
__global__ __launch_bounds__(256) void gat_aggregate(
    const int* __restrict__ row_off, const int* __restrict__ edge_ids,
    const int* __restrict__ src, const float* __restrict__ ew,
    const float* __restrict__ el, const float* __restrict__ er,
    const __half* __restrict__ feat_h, const float* __restrict__ out_w,
    const float* __restrict__ out_b, __half* __restrict__ hcat, int layer_off) {
    __shared__ float s_owt[32 * 33];      // out_w transposed [d][o]
    __shared__ int s_srcA[4][64];
    __shared__ float s_wA[4][64];
    __shared__ float s_aggA[4][16 * 33];  // epilogue staging

    int tid = threadIdx.x;
    for (int i = tid; i < 1024; i += 256) {
        int o = i >> 5, d = i & 31;
        s_owt[d * 33 + o] = out_w[i];
    }
    __syncthreads();  // only block-wide barrier; s_owt read-only afterwards

    int wv = tid >> 6, lane = tid & 63;
    int n = blockIdx.x * 4 + wv;
    int start = row_off[n], end = row_off[n + 1];
    int* s_src = s_srcA[wv];
    float* s_w = s_wA[wv];
    float* s_agg = s_aggA[wv];

    int bh4 = lane >> 2, sl = lane & 3;
    float er1 = er[(size_t)n * 16 + bh4];
    const float* el_base = el + bh4;             // el[s*16 + bh4]
    const __half* fbase = feat_h + lane * 8;     // feat[s*512 + lane*8]

    float den = 0.f;
    float acc8[8];
#pragma unroll
    for (int i = 0; i < 8; ++i) acc8[i] = 0.f;

    for (int base = start; base < end; base += 64) {
        int cnum = end - base;
        if (cnum > 64) cnum = 64;
        // stage edge data (wave-private LDS; same-wave program order)
        if (lane < cnum) {
            int eid = edge_ids[base + lane];
            s_src[lane] = src[eid];
            s_w[lane] = ew[eid];
        }
        // fused loop: score + exp + coalesced 1KB gather + FMA
#pragma unroll 8
        for (int j = 0; j < cnum; ++j) {
            int s = s_src[j];
            float sc = el_base[(size_t)s * 16] + er1;
            sc = sc > 0.f ? sc : 0.1f * sc;
            sc *= s_w[j];
            float p = __expf(sc);
            den += p;
            H8 u;
            u.f4 = *reinterpret_cast<const float4*>(fbase + (size_t)s * 512);
            float2 f0 = __half22float2(u.h2[0]);
            float2 f1 = __half22float2(u.h2[1]);
            float2 f2 = __half22float2(u.h2[2]);
            float2 f3 = __half22float2(u.h2[3]);
            acc8[0] += p * f0.x; acc8[1] += p * f0.y;
            acc8[2] += p * f1.x; acc8[3] += p * f1.y;
            acc8[4] += p * f2.x; acc8[5] += p * f2.y;
            acc8[6] += p * f3.x; acc8[7] += p * f3.y;
        }
    }

    // epilogue: normalize -> s_agg (wave-private), out_fc + relu -> hcat fp16
    float inv_den = (den == 0.f) ? 1.f : 1.f / den;
#pragma unroll
    for (int i = 0; i < 8; ++i) s_agg[bh4 * 33 + sl * 8 + i] = acc8[i] * inv_den;

    float o_acc[8];
#pragma unroll
    for (int i = 0; i < 8; ++i) o_acc[i] = out_b[sl * 8 + i];
#pragma unroll 8
    for (int dd = 0; dd < 32; ++dd) {
        float a = s_agg[bh4 * 33 + dd];
        const float* wr = s_owt + dd * 33 + sl * 8;
#pragma unroll
        for (int i = 0; i < 8; ++i) o_acc[i] += a * wr[i];
    }
    H8 ov;
#pragma unroll
    for (int k = 0; k < 4; ++k)
        ov.h2[k] = __floats2half2_rn(fmaxf(o_acc[2 * k], 0.f), fmaxf(o_acc[2 * k + 1], 0.f));
    // hcat row = n*4 + b, offset layer_off + h*32 + sl*8   (b = bh4>>2, h = bh4&3)
    int b = bh4 >> 2, h = bh4 & 3;
    *reinterpret_cast<float4*>(hcat + ((size_t)(n * 4 + b)) * 256 + layer_off + h * 32 + sl * 8) = ov.f4;
}

extern "C" void kernel_launch(void* const* d_in, const int* in_sizes, int n_in,
                              void* d_out, int out_size, void* d_ws, size_t ws_size,
                              hipStream_t stream) {
    const float* features = (const float*)d_in[0];
    const int* src = (const int*)d_in[1];
    const int* dst = (const int*)d_in[2];
    const float* edge_w = (const float*)d_in[3];
    const float* fc_w0 = (const float*)d_in[4];
    const float* al0 = (const float*)d_in[5];
    const float* ar0 = (const float*)d_in[6];
    const float* out_w0 = (const float*)d_in[7];
    const float* out_b0 = (const float*)d_in[8];
    const float* fc_w1 = (const float*)d_in[9];
    const float* al1 = (const float*)d_in[10];
    const float* ar1 = (const float*)d_in[11];
    const float* out_w1 = (const float*)d_in[12];
    const float* out_b1 = (const float*)d_in[13];
    const float* mlp_w = (const float*)d_in[14];
    const float* mlp_b = (const float*)d_in[15];
    float* out = (float*)d_out;

    char* p = (char*)d_ws;
    auto take = [&](size_t bytes) {
        char* cur = p;
        p += (bytes + 255) & ~(size_t)255;
        return cur;
    };
    __half* bp0 = (__half*)take(16384 * 2);
    __half* bp1 = (__half*)take(16384 * 2);
    __half* bpm = (__half*)take(32768 * 2);
    __half* feat_h = (__half*)take((size_t)BB * NN * 128 * 2);
    __half* hcat = (__half*)take((size_t)BB * NN * 256 * 2);
    float* el = (float*)take((size_t)BB * NN * HH * 4);
    float* er = (float*)take((size_t)BB * NN * HH * 4);
    int* cnt = (int*)take((size_t)NN * 4);
    int* cursor = (int*)take((size_t)NN * 4);
    int* row_off = (int*)take((size_t)(NN + 1) * 4);
    int* edge_ids = (int*)take((size_t)EE * 4);
    (void)ws_size; (void)in_sizes; (void)n_in; (void)out_size;

    // weight prep (+ counter zeroing) + CSR build
    pack_weights<<<128, 256, 0, stream>>>(fc_w0, fc_w1, mlp_w, bp0, bp1, bpm, cnt, cursor);
    count_edges<<<EE / 256, 256, 0, stream>>>(dst, cnt);
    scan_kernel<<<1, 1024, 0, stream>>>(cnt, row_off);
    scatter_edges<<<EE / 256, 256, 0, stream>>>(dst, row_off, cursor, edge_ids);

    const int GEMM_GRID = (BB * NN) / 64;  // 625
    const int AGG_GRID = NN / 4;  // 2500

    // ---- layer 0 ---- (A batch-major features -> node-major feat; fused el/er)
    mfma_gemm<128, 1, false, true, true, false><<<GEMM_GRID, 256, 0, stream>>>(
        features, 128, bp0, al0, ar0, nullptr, feat_h, nullptr, 128, el, er);
    gat_aggregate<<<AGG_GRID, 256, 0, stream>>>(row_off, edge_ids, src, edge_w, el, er,
                                                feat_h, out_w0, out_b0, hcat, 0);
    // ---- layer 1 ---- (A = hcat[:,0:128] node-major; identity remap; fused el/er)
    mfma_gemm<128, 0, true, true, true, false><<<GEMM_GRID, 256, 0, stream>>>(
        hcat, 256, bp1, al1, ar1, nullptr, feat_h, nullptr, 128, el, er);
    gat_aggregate<<<AGG_GRID, 256, 0, stream>>>(row_off, edge_ids, src, edge_w, el, er,
                                                feat_h, out_w1, out_b1, hcat, 128);
    // ---- MLP head ---- (A = hcat node-major, K=256; C-write back to batch-major out)
    mfma_gemm<256, 2, true, false, false, true><<<GEMM_GRID, 256, 0, stream>>>(
        hcat, 256, bpm, nullptr, nullptr, mlp_b, nullptr, out, 128, nullptr, nullptr);
}

// Round 14
// 196.349 us; speedup vs baseline: 1.2115x; 1.0371x over previous
//
#include <hip/hip_runtime.h>
#include <hip/hip_fp16.h>
#include <float.h>

#define NN 10000
#define EE 320000
#define BB 4
#define DD 128
#define HH 4
#define DHH 32

union H4 { uint2 u2; __half2 h2[2]; };
union H8 { float4 f4; __half2 h2[4]; };

typedef _Float16 f16x8 __attribute__((ext_vector_type(8)));
typedef float f32x4 __attribute__((ext_vector_type(4)));

// All intermediate tensors are NODE-MAJOR: row r = n*4 + b.
//   feat_h[r][128]; el/er[n*16 + b*4 + h]; hcat[r][256]
// features (input) and out (output) stay batch-major; GEMM C-writes remap.

// ---------------- prep: pack weights (blocks 0..127) || count edges (blocks 128..1377)
// cnt/cursor are zeroed by a preceding hipMemsetAsync, so pack and count can co-run.
__global__ void prep_kernel(const float* __restrict__ fc0, const float* __restrict__ fc1,
                            const float* __restrict__ mlp,
                            __half* __restrict__ bp0, __half* __restrict__ bp1,
                            __half* __restrict__ bpm,
                            const int* __restrict__ dst, int* __restrict__ cnt) {
    if (blockIdx.x < 128) {
        int s = blockIdx.x * 256 + threadIdx.x;  // 0..32767
        int i = s & 7, l = (s >> 3) & 63, ct = (s >> 9) & 7, kt = s >> 12;
        int k = kt * 32 + 8 * (l >> 4) + i;
        int o = ct * 16 + (l & 15);
        bpm[s] = __float2half(mlp[o * 256 + k]);
        if (s < 16384) {
            bp0[s] = __float2half(fc0[o * 128 + k]);
            bp1[s] = __float2half(fc1[o * 128 + k]);
        }
    } else {
        int e = (blockIdx.x - 128) * 256 + threadIdx.x;
        if (e < EE) atomicAdd(&cnt[dst[e]], 1);
    }
}

// ---------------- scan (R13 wave-shuffle version — proven) ----------------
__global__ void scan_kernel(const int* __restrict__ cnt, int* __restrict__ row_off) {
    __shared__ int part[16];
    int t = threadIdx.x;
    int lane = t & 63, wv = t >> 6;
    const int CH = 10;
    int loc[CH];
    int s = 0;
#pragma unroll
    for (int j = 0; j < CH; ++j) {
        int i = t * CH + j;
        int v = (i < NN) ? cnt[i] : 0;
        loc[j] = s;
        s += v;
    }
    int x = s;
#pragma unroll
    for (int off = 1; off < 64; off <<= 1) {
        int y = __shfl_up(x, off, 64);
        if (lane >= off) x += y;
    }
    if (lane == 63) part[wv] = x;
    __syncthreads();
    if (t == 0) {
        int a = 0;
#pragma unroll
        for (int w = 0; w < 16; ++w) { int v = part[w]; part[w] = a; a += v; }
    }
    __syncthreads();
    int base = part[wv] + (x - s);
#pragma unroll
    for (int j = 0; j < CH; ++j) {
        int i = t * CH + j;
        if (i < NN) row_off[i] = base + loc[j];
    }
    if (t == 1023) row_off[NN] = base + s;
}

// ---------------- GEMM body (R5-proven core as device fn; REMAP on C-row; optional el/er)
template <int K, int REMAP, bool A_HALF, bool ATTN, bool HALF_OUT, bool BIAS>
__device__ __forceinline__ void gemm_body(
    __half* A_s, const void* A_, int lda,
    const __half* __restrict__ Bp,
    const float* al, const float* ar, const float* bias,
    __half* outh, float* outf, int ldo,
    float* el_out, float* er_out, int block) {
    int tid = threadIdx.x;
    int row0 = block * 64;

    if (A_HALF) {
        const __half* A = (const __half*)A_;
#pragma unroll
        for (int it = 0; it < (64 * K / 8) / 256; ++it) {
            int s = it * 256 + tid;
            int r = s / (K / 8), c8 = s % (K / 8);
            uint4 v = *reinterpret_cast<const uint4*>(A + (size_t)(row0 + r) * lda + c8 * 8);
            int byte = (r * K + c8 * 8) * 2;
            byte ^= (r & 7) << 4;
            *reinterpret_cast<uint4*>((char*)A_s + byte) = v;
        }
    } else {
        const float* A = (const float*)A_;
#pragma unroll
        for (int it = 0; it < (64 * K / 4) / 256; ++it) {
            int s = it * 256 + tid;
            int r = s / (K / 4), c4 = s % (K / 4);
            float4 v = *reinterpret_cast<const float4*>(A + (size_t)(row0 + r) * lda + c4 * 4);
            __half h[4];
            h[0] = __float2half(v.x); h[1] = __float2half(v.y);
            h[2] = __float2half(v.z); h[3] = __float2half(v.w);
            int byte = (r * K + c4 * 4) * 2;
            byte ^= (r & 7) << 4;
            *reinterpret_cast<uint2*>((char*)A_s + byte) = *reinterpret_cast<uint2*>(h);
        }
    }
    __syncthreads();

    int l = tid & 63, w = tid >> 6;
    int g = l >> 4, r15 = l & 15;
    f32x4 acc[8] = {};

#pragma unroll
    for (int kt = 0; kt < K / 32; ++kt) {
        int row = w * 16 + r15;
        int byte = (row * K + kt * 32 + 8 * g) * 2;
        byte ^= (row & 7) << 4;
        f16x8 a = *reinterpret_cast<const f16x8*>((const char*)A_s + byte);
        const f16x8* bp = reinterpret_cast<const f16x8*>(Bp) + (size_t)(kt * 8) * 64 + l;
#pragma unroll
        for (int ct = 0; ct < 8; ++ct) {
            f16x8 b = bp[(size_t)ct * 64];
            acc[ct] = __builtin_amdgcn_mfma_f32_16x16x32_f16(a, b, acc[ct], 0, 0, 0);
        }
    }

    int grow[4];
#pragma unroll
    for (int reg = 0; reg < 4; ++reg) {
        int r = row0 + w * 16 + g * 4 + reg;
        if (REMAP == 0) grow[reg] = r;
        else if (REMAP == 1) { int n = r % NN, b = r / NN; grow[reg] = n * 4 + b; }
        else grow[reg] = (r & 3) * NN + (r >> 2);
    }
#pragma unroll
    for (int ct = 0; ct < 8; ++ct) {
        int col = ct * 16 + r15;
#pragma unroll
        for (int reg = 0; reg < 4; ++reg) {
            float v = acc[ct][reg];
            if (BIAS) v += bias[col];
            if (HALF_OUT) outh[(size_t)grow[reg] * ldo + col] = __float2half(v);
            else outf[(size_t)grow[reg] * ldo + col] = v;
        }
    }

    if (ATTN) {
#pragma unroll
        for (int h = 0; h < 4; ++h) {
            float a0 = al[(2 * h) * 16 + r15], a1 = al[(2 * h + 1) * 16 + r15];
            float b0 = ar[(2 * h) * 16 + r15], b1 = ar[(2 * h + 1) * 16 + r15];
            f32x4 pe, pr;
#pragma unroll
            for (int reg = 0; reg < 4; ++reg) {
                pe[reg] = acc[2 * h][reg] * a0 + acc[2 * h + 1][reg] * a1;
                pr[reg] = acc[2 * h][reg] * b0 + acc[2 * h + 1][reg] * b1;
            }
#pragma unroll
            for (int mk = 1; mk <= 8; mk <<= 1) {
#pragma unroll
                for (int reg = 0; reg < 4; ++reg) {
                    pe[reg] += __shfl_xor(pe[reg], mk, 64);
                    pr[reg] += __shfl_xor(pr[reg], mk, 64);
                }
            }
            if (r15 == 0) {
#pragma unroll
                for (int reg = 0; reg < 4; ++reg) {
                    el_out[grow[reg] * 4 + h] = pe[reg];
                    er_out[grow[reg] * 4 + h] = pr[reg];
                }
            }
        }
    }
}

template <int K, int REMAP, bool A_HALF, bool ATTN, bool HALF_OUT, bool BIAS>
__global__ __launch_bounds__(256) void mfma_gemm(
    const void* __restrict__ A_, int lda,
    const __half* __restrict__ Bp,
    const float* __restrict__ al, const float* __restrict__ ar,
    const float* __restrict__ bias,
    __half* __restrict__ outh, float* __restrict__ outf, int ldo,
    float* __restrict__ el_out, float* __restrict__ er_out) {
    __shared__ __half A_s[64 * K];
    gemm_body<K, REMAP, A_HALF, ATTN, HALF_OUT, BIAS>(
        A_s, A_, lda, Bp, al, ar, bias, outh, outf, ldo, el_out, er_out, blockIdx.x);
}

// ---------------- layer-0 GEMM (blocks 0..624) || scatter_edges (blocks 625..1874)
__global__ __launch_bounds__(256) void gemm0_scatter(
    const float* __restrict__ A, const __half* __restrict__ bp0,
    const float* __restrict__ al0, const float* __restrict__ ar0,
    __half* __restrict__ feat_h, float* __restrict__ el, float* __restrict__ er,
    const int* __restrict__ dst, const int* __restrict__ row_off,
    int* __restrict__ cursor, int* __restrict__ edge_ids) {
    __shared__ __half A_s[64 * 128];
    if (blockIdx.x >= 625) {
        int e = (blockIdx.x - 625) * 256 + threadIdx.x;
        if (e < EE) {
            int d = dst[e];
            int p = atomicAdd(&cursor[d], 1);
            edge_ids[row_off[d] + p] = e;
        }
        return;
    }
    gemm_body<128, 1, false, true, true, false>(
        A_s, A, 128, bp0, al0, ar0, nullptr, feat_h, nullptr, 128, el, er, blockIdx.x);
}

// ---------------- wave-per-node aggregate (verbatim R10/R13 — proven 53 us, replay-safe)
__global__ __launch_bounds__(256) void gat_aggregate(
    const int* __restrict__ row_off, const int* __restrict__ edge_ids,
    const int* __restrict__ src, const float* __restrict__ ew,
    const float* __restrict__ el, const float* __restrict__ er,
    const __half* __restrict__ feat_h, const float* __restrict__ out_w,
    const float* __restrict__ out_b, __half* __restrict__ hcat, int layer_off) {
    __shared__ float s_owt[32 * 33];      // out_w transposed [d][o]
    __shared__ int s_srcA[4][64];
    __shared__ float s_wA[4][64];
    __shared__ float s_aggA[4][16 * 33];  // epilogue staging

    int tid = threadIdx.x;
    for (int i = tid; i < 1024; i += 256) {
        int o = i >> 5, d = i & 31;
        s_owt[d * 33 + o] = out_w[i];
    }
    __syncthreads();  // only block-wide barrier; s_owt read-only afterwards

    int wv = tid >> 6, lane = tid & 63;
    int n = blockIdx.x * 4 + wv;
    int start = row_off[n], end = row_off[n + 1];
    int* s_src = s_srcA[wv];
    float* s_w = s_wA[wv];
    float* s_agg = s_aggA[wv];

    int bh4 = lane >> 2, sl = lane & 3;
    float er1 = er[(size_t)n * 16 + bh4];
    const float* el_base = el + bh4;             // el[s*16 + bh4]
    const __half* fbase = feat_h + lane * 8;     // feat[s*512 + lane*8]

    float den = 0.f;
    float acc8[8];
#pragma unroll
    for (int i = 0; i < 8; ++i) acc8[i] = 0.f;

    for (int base = start; base < end; base += 64) {
        int cnum = end - base;
        if (cnum > 64) cnum = 64;
        if (lane < cnum) {
            int eid = edge_ids[base + lane];
            s_src[lane] = src[eid];
            s_w[lane] = ew[eid];
        }
#pragma unroll 8
        for (int j = 0; j < cnum; ++j) {
            int s = s_src[j];
            float sc = el_base[(size_t)s * 16] + er1;
            sc = sc > 0.f ? sc : 0.1f * sc;
            sc *= s_w[j];
            float p = __expf(sc);
            den += p;
            H8 u;
            u.f4 = *reinterpret_cast<const float4*>(fbase + (size_t)s * 512);
            float2 f0 = __half22float2(u.h2[0]);
            float2 f1 = __half22float2(u.h2[1]);
            float2 f2 = __half22float2(u.h2[2]);
            float2 f3 = __half22float2(u.h2[3]);
            acc8[0] += p * f0.x; acc8[1] += p * f0.y;
            acc8[2] += p * f1.x; acc8[3] += p * f1.y;
            acc8[4] += p * f2.x; acc8[5] += p * f2.y;
            acc8[6] += p * f3.x; acc8[7] += p * f3.y;
        }
    }

    float inv_den = (den == 0.f) ? 1.f : 1.f / den;
#pragma unroll
    for (int i = 0; i < 8; ++i) s_agg[bh4 * 33 + sl * 8 + i] = acc8[i] * inv_den;

    float o_acc[8];
#pragma unroll
    for (int i = 0; i < 8; ++i) o_acc[i] = out_b[sl * 8 + i];
#pragma unroll 8
    for (int dd = 0; dd < 32; ++dd) {
        float a = s_agg[bh4 * 33 + dd];
        const float* wr = s_owt + dd * 33 + sl * 8;
#pragma unroll
        for (int i = 0; i < 8; ++i) o_acc[i] += a * wr[i];
    }
    H8 ov;
#pragma unroll
    for (int k = 0; k < 4; ++k)
        ov.h2[k] = __floats2half2_rn(fmaxf(o_acc[2 * k], 0.f), fmaxf(o_acc[2 * k + 1], 0.f));
    int b = bh4 >> 2, h = bh4 & 3;
    *reinterpret_cast<float4*>(hcat + ((size_t)(n * 4 + b)) * 256 + layer_off + h * 32 + sl * 8) = ov.f4;
}

extern "C" void kernel_launch(void* const* d_in, const int* in_sizes, int n_in,
                              void* d_out, int out_size, void* d_ws, size_t ws_size,
                              hipStream_t stream) {
    const float* features = (const float*)d_in[0];
    const int* src = (const int*)d_in[1];
    const int* dst = (const int*)d_in[2];
    const float* edge_w = (const float*)d_in[3];
    const float* fc_w0 = (const float*)d_in[4];
    const float* al0 = (const float*)d_in[5];
    const float* ar0 = (const float*)d_in[6];
    const float* out_w0 = (const float*)d_in[7];
    const float* out_b0 = (const float*)d_in[8];
    const float* fc_w1 = (const float*)d_in[9];
    const float* al1 = (const float*)d_in[10];
    const float* ar1 = (const float*)d_in[11];
    const float* out_w1 = (const float*)d_in[12];
    const float* out_b1 = (const float*)d_in[13];
    const float* mlp_w = (const float*)d_in[14];
    const float* mlp_b = (const float*)d_in[15];
    float* out = (float*)d_out;

    char* p = (char*)d_ws;
    auto take = [&](size_t bytes) {
        char* cur = p;
        p += (bytes + 255) & ~(size_t)255;
        return cur;
    };
    __half* bp0 = (__half*)take(16384 * 2);
    __half* bp1 = (__half*)take(16384 * 2);
    __half* bpm = (__half*)take(32768 * 2);
    __half* feat_h = (__half*)take((size_t)BB * NN * 128 * 2);
    __half* hcat = (__half*)take((size_t)BB * NN * 256 * 2);
    float* el = (float*)take((size_t)BB * NN * HH * 4);
    float* er = (float*)take((size_t)BB * NN * HH * 4);
    int* cnt = (int*)take((size_t)NN * 4);       // cnt and cursor are contiguous:
    int* cursor = (int*)take((size_t)NN * 4);    // one memset covers both
    int* row_off = (int*)take((size_t)(NN + 1) * 4);
    int* edge_ids = (int*)take((size_t)EE * 4);
    (void)ws_size; (void)in_sizes; (void)n_in; (void)out_size;

    size_t zbytes = (size_t)((char*)cursor - (char*)cnt) + (size_t)NN * 4;
    hipMemsetAsync(cnt, 0, zbytes, stream);

    // prep: pack weights || count edges
    prep_kernel<<<128 + EE / 256, 256, 0, stream>>>(fc_w0, fc_w1, mlp_w, bp0, bp1, bpm, dst, cnt);
    scan_kernel<<<1, 1024, 0, stream>>>(cnt, row_off);

    const int GEMM_GRID = (BB * NN) / 64;  // 625
    const int AGG_GRID = NN / 4;           // 2500

    // ---- layer 0 GEMM (fused el/er) || scatter_edges ----
    gemm0_scatter<<<GEMM_GRID + EE / 256, 256, 0, stream>>>(
        features, bp0, al0, ar0, feat_h, el, er, dst, row_off, cursor, edge_ids);
    gat_aggregate<<<AGG_GRID, 256, 0, stream>>>(row_off, edge_ids, src, edge_w, el, er,
                                                feat_h, out_w0, out_b0, hcat, 0);
    // ---- layer 1 ---- (A = hcat[:,0:128] node-major; identity remap; fused el/er)
    mfma_gemm<128, 0, true, true, true, false><<<GEMM_GRID, 256, 0, stream>>>(
        hcat, 256, bp1, al1, ar1, nullptr, feat_h, nullptr, 128, el, er);
    gat_aggregate<<<AGG_GRID, 256, 0, stream>>>(row_off, edge_ids, src, edge_w, el, er,
                                                feat_h, out_w1, out_b1, hcat, 128);
    // ---- MLP head ---- (A = hcat node-major, K=256; C-write back to batch-major out)
    mfma_gemm<256, 2, true, false, false, true><<<GEMM_GRID, 256, 0, stream>>>(
        hcat, 256, bpm, nullptr, nullptr, mlp_b, nullptr, out, 128, nullptr, nullptr);
}

// Round 15
// 195.149 us; speedup vs baseline: 1.2190x; 1.0062x over previous
//
#include <hip/hip_runtime.h>
#include <hip/hip_fp16.h>
#include <float.h>

#define NN 10000
#define EE 320000
#define BB 4
#define DD 128
#define HH 4
#define DHH 32

union H4 { uint2 u2; __half2 h2[2]; };
union H8 { float4 f4; __half2 h2[4]; };

typedef _Float16 f16x8 __attribute__((ext_vector_type(8)));
typedef float f32x4 __attribute__((ext_vector_type(4)));

// All intermediate tensors are NODE-MAJOR: row r = n*4 + b.
//   feat_h[r][128]; el/er[n*16 + b*4 + h]; hcat[r][256]
// features (input) and out (output) stay batch-major; GEMM C-writes remap.
// MLP is split: out = x1*W1^T + bias (co-runs with layer-1 GEMM), then out += x2*W2^T.

// ---------------- prep: pack weights (blocks 0..127) || count edges (blocks 128..1377)
__global__ void prep_kernel(const float* __restrict__ fc0, const float* __restrict__ fc1,
                            const float* __restrict__ mlp,
                            __half* __restrict__ bp0, __half* __restrict__ bp1,
                            __half* __restrict__ bpm,
                            const int* __restrict__ dst, int* __restrict__ cnt) {
    if (blockIdx.x < 128) {
        int s = blockIdx.x * 256 + threadIdx.x;  // 0..32767
        int i = s & 7, l = (s >> 3) & 63, ct = (s >> 9) & 7, kt = s >> 12;
        int k = kt * 32 + 8 * (l >> 4) + i;
        int o = ct * 16 + (l & 15);
        bpm[s] = __float2half(mlp[o * 256 + k]);
        if (s < 16384) {
            bp0[s] = __float2half(fc0[o * 128 + k]);
            bp1[s] = __float2half(fc1[o * 128 + k]);
        }
    } else {
        int e = (blockIdx.x - 128) * 256 + threadIdx.x;
        if (e < EE) atomicAdd(&cnt[dst[e]], 1);
    }
}

// ---------------- scan (wave-shuffle, proven) ----------------
__global__ void scan_kernel(const int* __restrict__ cnt, int* __restrict__ row_off) {
    __shared__ int part[16];
    int t = threadIdx.x;
    int lane = t & 63, wv = t >> 6;
    const int CH = 10;
    int loc[CH];
    int s = 0;
#pragma unroll
    for (int j = 0; j < CH; ++j) {
        int i = t * CH + j;
        int v = (i < NN) ? cnt[i] : 0;
        loc[j] = s;
        s += v;
    }
    int x = s;
#pragma unroll
    for (int off = 1; off < 64; off <<= 1) {
        int y = __shfl_up(x, off, 64);
        if (lane >= off) x += y;
    }
    if (lane == 63) part[wv] = x;
    __syncthreads();
    if (t == 0) {
        int a = 0;
#pragma unroll
        for (int w = 0; w < 16; ++w) { int v = part[w]; part[w] = a; a += v; }
    }
    __syncthreads();
    int base = part[wv] + (x - s);
#pragma unroll
    for (int j = 0; j < CH; ++j) {
        int i = t * CH + j;
        if (i < NN) row_off[i] = base + loc[j];
    }
    if (t == 1023) row_off[NN] = base + s;
}

// ---------------- GEMM body (R5-proven core; REMAP on C-row; optional el/er; optional +=)
template <int K, int REMAP, bool A_HALF, bool ATTN, bool HALF_OUT, bool BIAS, bool ACCUM>
__device__ __forceinline__ void gemm_body(
    __half* A_s, const void* A_, int lda,
    const __half* __restrict__ Bp,
    const float* al, const float* ar, const float* bias,
    __half* outh, float* outf, int ldo,
    float* el_out, float* er_out, int block) {
    int tid = threadIdx.x;
    int row0 = block * 64;

    if (A_HALF) {
        const __half* A = (const __half*)A_;
#pragma unroll
        for (int it = 0; it < (64 * K / 8) / 256; ++it) {
            int s = it * 256 + tid;
            int r = s / (K / 8), c8 = s % (K / 8);
            uint4 v = *reinterpret_cast<const uint4*>(A + (size_t)(row0 + r) * lda + c8 * 8);
            int byte = (r * K + c8 * 8) * 2;
            byte ^= (r & 7) << 4;
            *reinterpret_cast<uint4*>((char*)A_s + byte) = v;
        }
    } else {
        const float* A = (const float*)A_;
#pragma unroll
        for (int it = 0; it < (64 * K / 4) / 256; ++it) {
            int s = it * 256 + tid;
            int r = s / (K / 4), c4 = s % (K / 4);
            float4 v = *reinterpret_cast<const float4*>(A + (size_t)(row0 + r) * lda + c4 * 4);
            __half h[4];
            h[0] = __float2half(v.x); h[1] = __float2half(v.y);
            h[2] = __float2half(v.z); h[3] = __float2half(v.w);
            int byte = (r * K + c4 * 4) * 2;
            byte ^= (r & 7) << 4;
            *reinterpret_cast<uint2*>((char*)A_s + byte) = *reinterpret_cast<uint2*>(h);
        }
    }
    __syncthreads();

    int l = tid & 63, w = tid >> 6;
    int g = l >> 4, r15 = l & 15;
    f32x4 acc[8] = {};

#pragma unroll
    for (int kt = 0; kt < K / 32; ++kt) {
        int row = w * 16 + r15;
        int byte = (row * K + kt * 32 + 8 * g) * 2;
        byte ^= (row & 7) << 4;
        f16x8 a = *reinterpret_cast<const f16x8*>((const char*)A_s + byte);
        const f16x8* bp = reinterpret_cast<const f16x8*>(Bp) + (size_t)(kt * 8) * 64 + l;
#pragma unroll
        for (int ct = 0; ct < 8; ++ct) {
            f16x8 b = bp[(size_t)ct * 64];
            acc[ct] = __builtin_amdgcn_mfma_f32_16x16x32_f16(a, b, acc[ct], 0, 0, 0);
        }
    }

    int grow[4];
#pragma unroll
    for (int reg = 0; reg < 4; ++reg) {
        int r = row0 + w * 16 + g * 4 + reg;
        if (REMAP == 0) grow[reg] = r;
        else if (REMAP == 1) { int n = r % NN, b = r / NN; grow[reg] = n * 4 + b; }
        else grow[reg] = (r & 3) * NN + (r >> 2);
    }
#pragma unroll
    for (int ct = 0; ct < 8; ++ct) {
        int col = ct * 16 + r15;
#pragma unroll
        for (int reg = 0; reg < 4; ++reg) {
            float v = acc[ct][reg];
            if (BIAS) v += bias[col];
            if (HALF_OUT) outh[(size_t)grow[reg] * ldo + col] = __float2half(v);
            else if (ACCUM) outf[(size_t)grow[reg] * ldo + col] += v;
            else outf[(size_t)grow[reg] * ldo + col] = v;
        }
    }

    if (ATTN) {
#pragma unroll
        for (int h = 0; h < 4; ++h) {
            float a0 = al[(2 * h) * 16 + r15], a1 = al[(2 * h + 1) * 16 + r15];
            float b0 = ar[(2 * h) * 16 + r15], b1 = ar[(2 * h + 1) * 16 + r15];
            f32x4 pe, pr;
#pragma unroll
            for (int reg = 0; reg < 4; ++reg) {
                pe[reg] = acc[2 * h][reg] * a0 + acc[2 * h + 1][reg] * a1;
                pr[reg] = acc[2 * h][reg] * b0 + acc[2 * h + 1][reg] * b1;
            }
#pragma unroll
            for (int mk = 1; mk <= 8; mk <<= 1) {
#pragma unroll
                for (int reg = 0; reg < 4; ++reg) {
                    pe[reg] += __shfl_xor(pe[reg], mk, 64);
                    pr[reg] += __shfl_xor(pr[reg], mk, 64);
                }
            }
            if (r15 == 0) {
#pragma unroll
                for (int reg = 0; reg < 4; ++reg) {
                    el_out[grow[reg] * 4 + h] = pe[reg];
                    er_out[grow[reg] * 4 + h] = pr[reg];
                }
            }
        }
    }
}

template <int K, int REMAP, bool A_HALF, bool ATTN, bool HALF_OUT, bool BIAS, bool ACCUM>
__global__ __launch_bounds__(256) void mfma_gemm(
    const void* __restrict__ A_, int lda,
    const __half* __restrict__ Bp,
    const float* __restrict__ al, const float* __restrict__ ar,
    const float* __restrict__ bias,
    __half* __restrict__ outh, float* __restrict__ outf, int ldo,
    float* __restrict__ el_out, float* __restrict__ er_out) {
    __shared__ __half A_s[64 * K];
    gemm_body<K, REMAP, A_HALF, ATTN, HALF_OUT, BIAS, ACCUM>(
        A_s, A_, lda, Bp, al, ar, bias, outh, outf, ldo, el_out, er_out, blockIdx.x);
}

// ---------------- layer-0 GEMM (blocks 0..624) || scatter_edges (blocks 625..1874)
__global__ __launch_bounds__(256) void gemm0_scatter(
    const float* __restrict__ A, const __half* __restrict__ bp0,
    const float* __restrict__ al0, const float* __restrict__ ar0,
    __half* __restrict__ feat_h, float* __restrict__ el, float* __restrict__ er,
    const int* __restrict__ dst, const int* __restrict__ row_off,
    int* __restrict__ cursor, int* __restrict__ edge_ids) {
    __shared__ __half A_s[64 * 128];
    if (blockIdx.x >= 625) {
        int e = (blockIdx.x - 625) * 256 + threadIdx.x;
        if (e < EE) {
            int d = dst[e];
            int p = atomicAdd(&cursor[d], 1);
            edge_ids[row_off[d] + p] = e;
        }
        return;
    }
    gemm_body<128, 1, false, true, true, false, false>(
        A_s, A, 128, bp0, al0, ar0, nullptr, feat_h, nullptr, 128, el, er, blockIdx.x);
}

// ---------------- layer-1 GEMM (blocks 0..624) || MLP part-1 (blocks 625..1249)
// MLP part-1: out = x1 * W1^T + bias  (x1 = hcat[:,0:128], W1 = bpm kt 0..3)
__global__ __launch_bounds__(256) void gemm1_mlp1(
    const __half* __restrict__ hcat, const __half* __restrict__ bp1,
    const __half* __restrict__ bpm,
    const float* __restrict__ al1, const float* __restrict__ ar1,
    const float* __restrict__ mlp_b,
    __half* __restrict__ feat_h, float* __restrict__ el, float* __restrict__ er,
    float* __restrict__ out) {
    __shared__ __half A_s[64 * 128];
    if (blockIdx.x < 625) {
        gemm_body<128, 0, true, true, true, false, false>(
            A_s, hcat, 256, bp1, al1, ar1, nullptr, feat_h, nullptr, 128, el, er, blockIdx.x);
    } else {
        gemm_body<128, 2, true, false, false, true, false>(
            A_s, hcat, 256, bpm, nullptr, nullptr, mlp_b, nullptr, out, 128,
            nullptr, nullptr, blockIdx.x - 625);
    }
}

// ---------------- wave-per-node aggregate (verbatim R10/R13 — proven, replay-safe)
__global__ __launch_bounds__(256) void gat_aggregate(
    const int* __restrict__ row_off, const int* __restrict__ edge_ids,
    const int* __restrict__ src, const float* __restrict__ ew,
    const float* __restrict__ el, const float* __restrict__ er,
    const __half* __restrict__ feat_h, const float* __restrict__ out_w,
    const float* __restrict__ out_b, __half* __restrict__ hcat, int layer_off) {
    __shared__ float s_owt[32 * 33];
    __shared__ int s_srcA[4][64];
    __shared__ float s_wA[4][64];
    __shared__ float s_aggA[4][16 * 33];

    int tid = threadIdx.x;
    for (int i = tid; i < 1024; i += 256) {
        int o = i >> 5, d = i & 31;
        s_owt[d * 33 + o] = out_w[i];
    }
    __syncthreads();

    int wv = tid >> 6, lane = tid & 63;
    int n = blockIdx.x * 4 + wv;
    int start = row_off[n], end = row_off[n + 1];
    int* s_src = s_srcA[wv];
    float* s_w = s_wA[wv];
    float* s_agg = s_aggA[wv];

    int bh4 = lane >> 2, sl = lane & 3;
    float er1 = er[(size_t)n * 16 + bh4];
    const float* el_base = el + bh4;
    const __half* fbase = feat_h + lane * 8;

    float den = 0.f;
    float acc8[8];
#pragma unroll
    for (int i = 0; i < 8; ++i) acc8[i] = 0.f;

    for (int base = start; base < end; base += 64) {
        int cnum = end - base;
        if (cnum > 64) cnum = 64;
        if (lane < cnum) {
            int eid = edge_ids[base + lane];
            s_src[lane] = src[eid];
            s_w[lane] = ew[eid];
        }
#pragma unroll 8
        for (int j = 0; j < cnum; ++j) {
            int s = s_src[j];
            float sc = el_base[(size_t)s * 16] + er1;
            sc = sc > 0.f ? sc : 0.1f * sc;
            sc *= s_w[j];
            float p = __expf(sc);
            den += p;
            H8 u;
            u.f4 = *reinterpret_cast<const float4*>(fbase + (size_t)s * 512);
            float2 f0 = __half22float2(u.h2[0]);
            float2 f1 = __half22float2(u.h2[1]);
            float2 f2 = __half22float2(u.h2[2]);
            float2 f3 = __half22float2(u.h2[3]);
            acc8[0] += p * f0.x; acc8[1] += p * f0.y;
            acc8[2] += p * f1.x; acc8[3] += p * f1.y;
            acc8[4] += p * f2.x; acc8[5] += p * f2.y;
            acc8[6] += p * f3.x; acc8[7] += p * f3.y;
        }
    }

    float inv_den = (den == 0.f) ? 1.f : 1.f / den;
#pragma unroll
    for (int i = 0; i < 8; ++i) s_agg[bh4 * 33 + sl * 8 + i] = acc8[i] * inv_den;

    float o_acc[8];
#pragma unroll
    for (int i = 0; i < 8; ++i) o_acc[i] = out_b[sl * 8 + i];
#pragma unroll 8
    for (int dd = 0; dd < 32; ++dd) {
        float a = s_agg[bh4 * 33 + dd];
        const float* wr = s_owt + dd * 33 + sl * 8;
#pragma unroll
        for (int i = 0; i < 8; ++i) o_acc[i] += a * wr[i];
    }
    H8 ov;
#pragma unroll
    for (int k = 0; k < 4; ++k)
        ov.h2[k] = __floats2half2_rn(fmaxf(o_acc[2 * k], 0.f), fmaxf(o_acc[2 * k + 1], 0.f));
    int b = bh4 >> 2, h = bh4 & 3;
    *reinterpret_cast<float4*>(hcat + ((size_t)(n * 4 + b)) * 256 + layer_off + h * 32 + sl * 8) = ov.f4;
}

extern "C" void kernel_launch(void* const* d_in, const int* in_sizes, int n_in,
                              void* d_out, int out_size, void* d_ws, size_t ws_size,
                              hipStream_t stream) {
    const float* features = (const float*)d_in[0];
    const int* src = (const int*)d_in[1];
    const int* dst = (const int*)d_in[2];
    const float* edge_w = (const float*)d_in[3];
    const float* fc_w0 = (const float*)d_in[4];
    const float* al0 = (const float*)d_in[5];
    const float* ar0 = (const float*)d_in[6];
    const float* out_w0 = (const float*)d_in[7];
    const float* out_b0 = (const float*)d_in[8];
    const float* fc_w1 = (const float*)d_in[9];
    const float* al1 = (const float*)d_in[10];
    const float* ar1 = (const float*)d_in[11];
    const float* out_w1 = (const float*)d_in[12];
    const float* out_b1 = (const float*)d_in[13];
    const float* mlp_w = (const float*)d_in[14];
    const float* mlp_b = (const float*)d_in[15];
    float* out = (float*)d_out;

    char* p = (char*)d_ws;
    auto take = [&](size_t bytes) {
        char* cur = p;
        p += (bytes + 255) & ~(size_t)255;
        return cur;
    };
    __half* bp0 = (__half*)take(16384 * 2);
    __half* bp1 = (__half*)take(16384 * 2);
    __half* bpm = (__half*)take(32768 * 2);
    __half* feat_h = (__half*)take((size_t)BB * NN * 128 * 2);
    __half* hcat = (__half*)take((size_t)BB * NN * 256 * 2);
    float* el = (float*)take((size_t)BB * NN * HH * 4);
    float* er = (float*)take((size_t)BB * NN * HH * 4);
    int* cnt = (int*)take((size_t)NN * 4);       // cnt and cursor contiguous:
    int* cursor = (int*)take((size_t)NN * 4);    // one memset covers both
    int* row_off = (int*)take((size_t)(NN + 1) * 4);
    int* edge_ids = (int*)take((size_t)EE * 4);
    (void)ws_size; (void)in_sizes; (void)n_in; (void)out_size;

    size_t zbytes = (size_t)((char*)cursor - (char*)cnt) + (size_t)NN * 4;
    hipMemsetAsync(cnt, 0, zbytes, stream);

    prep_kernel<<<128 + EE / 256, 256, 0, stream>>>(fc_w0, fc_w1, mlp_w, bp0, bp1, bpm, dst, cnt);
    scan_kernel<<<1, 1024, 0, stream>>>(cnt, row_off);

    const int GEMM_GRID = (BB * NN) / 64;  // 625
    const int AGG_GRID = NN / 4;           // 2500

    // ---- layer 0 GEMM (fused el/er) || scatter_edges ----
    gemm0_scatter<<<GEMM_GRID + EE / 256, 256, 0, stream>>>(
        features, bp0, al0, ar0, feat_h, el, er, dst, row_off, cursor, edge_ids);
    gat_aggregate<<<AGG_GRID, 256, 0, stream>>>(row_off, edge_ids, src, edge_w, el, er,
                                                feat_h, out_w0, out_b0, hcat, 0);
    // ---- layer 1 GEMM (fused el/er) || MLP part-1 (out = x1*W1^T + bias) ----
    gemm1_mlp1<<<2 * GEMM_GRID, 256, 0, stream>>>(
        hcat, bp1, bpm, al1, ar1, mlp_b, feat_h, el, er, out);
    gat_aggregate<<<AGG_GRID, 256, 0, stream>>>(row_off, edge_ids, src, edge_w, el, er,
                                                feat_h, out_w1, out_b1, hcat, 128);
    // ---- MLP part-2: out += x2*W2^T (x2 = hcat[:,128:256], W2 = bpm kt 4..7) ----
    mfma_gemm<128, 2, true, false, false, false, true><<<GEMM_GRID, 256, 0, stream>>>(
        hcat + 128, 256, bpm + 16384, nullptr, nullptr, nullptr,
        nullptr, out, 128, nullptr, nullptr);
}